// Round 3
// baseline (2603.241 us; speedup 1.0000x reference)
//
#include <hip/hip_runtime.h>
#include <hip/hip_bf16.h>

#define N_ENT_C   100000
#define N_EDGE_C  500000
#define N_SEED_C  10000
#define DIM_C     128

typedef __hip_bfloat16 bf16;

// Detect whether a "float" input buffer is fp32 (flag=1) or packed bf16 (flag=0).
// fp32 (incl. bf16-rounded-to-fp32, whose low 16 bits are 0): low-half exponent
// field is <96 often (always, if low bits are 0). Packed bf16 N(0,1): low half is
// a real bf16 value, exp field <96 would mean |v|<2^-31 -> never.
__global__ void k_detect(const unsigned int* __restrict__ words, int* __restrict__ flag) {
  if (blockIdx.x == 0 && threadIdx.x == 0) {
    int cnt = 0;
    for (int i = 0; i < 64; ++i) {
      unsigned int e = (words[i] >> 7) & 0xFF;
      cnt += (e < 96) ? 1 : 0;
    }
    *flag = (cnt >= 8) ? 1 : 0;  // 1 = fp32, 0 = bf16
  }
}

__global__ void k_fill1(float* __restrict__ p, int n) {
  int i = blockIdx.x * 256 + threadIdx.x;
  if (i < n) p[i] = 1.0f;
}

__global__ void k_zero4(float4* __restrict__ p, int n4) {
  int i = blockIdx.x * 256 + threadIdx.x;
  if (i < n4) p[i] = make_float4(0.f, 0.f, 0.f, 0.f);
}

__global__ void k_degree(const int* __restrict__ edges, float* __restrict__ deg, int E) {
  int e = blockIdx.x * 256 + threadIdx.x;
  if (e < E) {
    int a = edges[2 * e];
    int b = edges[2 * e + 1];
    atomicAdd(&deg[a], 1.0f);
    atomicAdd(&deg[b], 1.0f);
  }
}

__global__ void k_rsqrt(float* __restrict__ p, int n) {
  int i = blockIdx.x * 256 + threadIdx.x;
  if (i < n) p[i] = rsqrtf(p[i]);
}

// dtype-flexible convert: src is fp32 (flag=1) or bf16 (flag=0) -> fp32 dst
__global__ void k_cvt_auto(const void* __restrict__ src, float* __restrict__ dst,
                           const int* __restrict__ flag, int n) {
  int i = blockIdx.x * 256 + threadIdx.x;
  if (i >= n) return;
  if (*flag) dst[i] = ((const float*)src)[i];
  else       dst[i] = __bfloat162float(((const bf16*)src)[i]);
}

// agg_pre[d,:] += x[s,:] * rdeg[s]  over all 1M directed edges.
// 2 directed edges per 256-thread block (128 dims each).
__global__ void k_scatter(const int* __restrict__ edges, const float* __restrict__ x,
                          const float* __restrict__ rdeg, float* __restrict__ agg, int E) {
  int t = blockIdx.x * 256 + threadIdx.x;
  int e = t >> 7;
  int dim = t & 127;
  if (e >= 2 * E) return;
  int s, d;
  if (e < E) { s = edges[2 * e];           d = edges[2 * e + 1]; }
  else       { s = edges[2 * (e - E) + 1]; d = edges[2 * (e - E)]; }
  float v = x[(size_t)s * DIM_C + dim] * rdeg[s];
  atomicAdd(&agg[(size_t)d * DIM_C + dim], v);
}

// x = relu( A @ W + x ),  A[i,k] = rdeg[i]*agg_pre[i,k] + rdeg[i]^2*x[i,k]
// In-place over x: each output element is read(residual)-then-written by its
// owner thread only. BM=32 rows/block; K split in two 64-halves; LDS 48KB.
__global__ __launch_bounds__(256, 2) void k_gemm(
    float* __restrict__ x, const float* __restrict__ agg,
    const float* __restrict__ rdeg, const void* __restrict__ W,
    const int* __restrict__ flag, int n) {
  __shared__ float sW[64 * DIM_C];
  __shared__ float sA[32 * DIM_C];
  int isf32 = *flag;
  int row0 = blockIdx.x * 32;
  for (int i = threadIdx.x; i < 32 * DIM_C; i += 256) {
    int r = row0 + (i >> 7);
    int k = i & 127;
    float rd = rdeg[r];
    sA[i] = rd * agg[(size_t)r * DIM_C + k] + rd * rd * x[(size_t)r * DIM_C + k];
  }
  int tc = (threadIdx.x & 31) * 4;   // 4 output cols
  int tr = (threadIdx.x >> 5) * 4;   // 4 output rows
  float acc[4][4] = {};
  for (int kh = 0; kh < 2; ++kh) {
    __syncthreads();                  // sW reuse barrier (also covers sA on kh=0)
    for (int i = threadIdx.x; i < 64 * DIM_C; i += 256) {
      int off = kh * 64 * DIM_C + i;
      sW[i] = isf32 ? ((const float*)W)[off]
                    : __bfloat162float(((const bf16*)W)[off]);
    }
    __syncthreads();
#pragma unroll 8
    for (int k = 0; k < 64; ++k) {
      float4 w = *(const float4*)&sW[k * DIM_C + tc];
      int kk = kh * 64 + k;
      float a0 = sA[(tr + 0) * DIM_C + kk];
      float a1 = sA[(tr + 1) * DIM_C + kk];
      float a2 = sA[(tr + 2) * DIM_C + kk];
      float a3 = sA[(tr + 3) * DIM_C + kk];
      acc[0][0] = fmaf(a0, w.x, acc[0][0]); acc[0][1] = fmaf(a0, w.y, acc[0][1]);
      acc[0][2] = fmaf(a0, w.z, acc[0][2]); acc[0][3] = fmaf(a0, w.w, acc[0][3]);
      acc[1][0] = fmaf(a1, w.x, acc[1][0]); acc[1][1] = fmaf(a1, w.y, acc[1][1]);
      acc[1][2] = fmaf(a1, w.z, acc[1][2]); acc[1][3] = fmaf(a1, w.w, acc[1][3]);
      acc[2][0] = fmaf(a2, w.x, acc[2][0]); acc[2][1] = fmaf(a2, w.y, acc[2][1]);
      acc[2][2] = fmaf(a2, w.z, acc[2][2]); acc[2][3] = fmaf(a2, w.w, acc[2][3]);
      acc[3][0] = fmaf(a3, w.x, acc[3][0]); acc[3][1] = fmaf(a3, w.y, acc[3][1]);
      acc[3][2] = fmaf(a3, w.z, acc[3][2]); acc[3][3] = fmaf(a3, w.w, acc[3][3]);
    }
  }
  for (int r = 0; r < 4; ++r) {
    int row = row0 + tr + r;
    if (row >= n) break;
    float4 res = *(const float4*)&x[(size_t)row * DIM_C + tc];
    float4 o;
    o.x = fmaxf(acc[r][0] + res.x, 0.f);
    o.y = fmaxf(acc[r][1] + res.y, 0.f);
    o.z = fmaxf(acc[r][2] + res.z, 0.f);
    o.w = fmaxf(acc[r][3] + res.w, 0.f);
    *(float4*)&x[(size_t)row * DIM_C + tc] = o;
  }
}

__global__ void k_out_ent(const float4* __restrict__ x, float4* __restrict__ out, int n4) {
  int i = blockIdx.x * 256 + threadIdx.x;
  if (i < n4) out[i] = x[i];
}

__global__ void k_out_seed(const float* __restrict__ x, const int* __restrict__ seeds,
                           float* __restrict__ out, int total) {
  int t = blockIdx.x * 256 + threadIdx.x;
  if (t < total) {
    int s = t >> 7;
    int dim = t & 127;
    out[t] = x[(size_t)seeds[s] * DIM_C + dim];
  }
}

extern "C" void kernel_launch(void* const* d_in, const int* in_sizes, int n_in,
                              void* d_out, int out_size, void* d_ws, size_t ws_size,
                              hipStream_t stream) {
  const int*  sr_seeds = (const int*)d_in[0];
  const int*  tg_seeds = (const int*)d_in[1];
  // d_in[2], d_in[3]: triples_* — unused by the reference.
  const void* emb_sr   = d_in[4];
  const void* emb_tg   = d_in[5];
  const int*  edges_sr = (const int*)d_in[6];
  const int*  edges_tg = (const int*)d_in[7];
  const void* W1       = d_in[8];
  const void* W2       = d_in[9];
  float* out = (float*)d_out;

  const int nd = N_ENT_C * DIM_C;  // 12,800,000
  float* ws_x    = (float*)d_ws;
  float* ws_agg  = ws_x + (size_t)nd;
  float* ws_rdeg = ws_agg + (size_t)nd;
  int*   ws_flag = (int*)(ws_rdeg + N_ENT_C);   // total ~102.8 MB of d_ws

  float* out_seed_sr = out;
  float* out_seed_tg = out + (size_t)N_SEED_C * DIM_C;
  float* out_ent_sr  = out + (size_t)2 * N_SEED_C * DIM_C;
  float* out_ent_tg  = out_ent_sr + (size_t)nd;

  const void* Ws[2] = {W1, W2};

  struct G { const void* emb; const int* edges; const int* seeds; float* oent; float* oseed; };
  G gs[2] = {
    {emb_sr, edges_sr, sr_seeds, out_ent_sr, out_seed_sr},
    {emb_tg, edges_tg, tg_seeds, out_ent_tg, out_seed_tg},
  };

  k_detect<<<1, 64, 0, stream>>>((const unsigned int*)emb_sr, ws_flag);

  for (int g = 0; g < 2; ++g) {
    k_fill1 <<<(N_ENT_C + 255) / 256, 256, 0, stream>>>(ws_rdeg, N_ENT_C);
    k_degree<<<(N_EDGE_C + 255) / 256, 256, 0, stream>>>(gs[g].edges, ws_rdeg, N_EDGE_C);
    k_rsqrt <<<(N_ENT_C + 255) / 256, 256, 0, stream>>>(ws_rdeg, N_ENT_C);
    k_cvt_auto<<<(nd + 255) / 256, 256, 0, stream>>>(gs[g].emb, ws_x, ws_flag, nd);
    for (int l = 0; l < 2; ++l) {
      k_zero4  <<<(nd / 4 + 255) / 256, 256, 0, stream>>>((float4*)ws_agg, nd / 4);
      k_scatter<<<N_EDGE_C, 256, 0, stream>>>(gs[g].edges, ws_x, ws_rdeg, ws_agg, N_EDGE_C);
      k_gemm   <<<N_ENT_C / 32, 256, 0, stream>>>(ws_x, ws_agg, ws_rdeg, Ws[l], ws_flag, N_ENT_C);
    }
    k_out_ent <<<(nd / 4 + 255) / 256, 256, 0, stream>>>((const float4*)ws_x, (float4*)gs[g].oent, nd / 4);
    k_out_seed<<<(N_SEED_C * DIM_C + 255) / 256, 256, 0, stream>>>(ws_x, gs[g].seeds, gs[g].oseed, N_SEED_C * DIM_C);
  }
}

// Round 4
// 1349.245 us; speedup vs baseline: 1.9294x; 1.9294x over previous
//
#include <hip/hip_runtime.h>
#include <hip/hip_bf16.h>

#define N_ENT_C   100000
#define N_EDGE_C  500000
#define N_SEED_C  10000
#define DIM_C     128

typedef __hip_bfloat16 bf16;

// Detect whether a "float" input buffer is fp32 (flag=1) or packed bf16 (flag=0).
__global__ void k_detect(const unsigned int* __restrict__ words, int* __restrict__ flag) {
  if (blockIdx.x == 0 && threadIdx.x == 0) {
    int cnt = 0;
    for (int i = 0; i < 64; ++i) {
      unsigned int e = (words[i] >> 7) & 0xFF;
      cnt += (e < 96) ? 1 : 0;
    }
    *flag = (cnt >= 8) ? 1 : 0;  // 1 = fp32, 0 = bf16
  }
}

__global__ void k_zero_int(int* __restrict__ p, int n) {
  int i = blockIdx.x * 256 + threadIdx.x;
  if (i < n) p[i] = 0;
}

// int degree count over undirected edges (both endpoints).
__global__ void k_count(const int2* __restrict__ edges, int* __restrict__ deg, int E) {
  int e = blockIdx.x * 256 + threadIdx.x;
  if (e < E) {
    int2 ed = edges[e];
    atomicAdd(&deg[ed.x], 1);
    atomicAdd(&deg[ed.y], 1);
  }
}

// rdeg[i] = rsqrt(deg[i] + 1)   (+1 = self loop)
__global__ void k_rdeg(const int* __restrict__ deg, float* __restrict__ rdeg, int n) {
  int i = blockIdx.x * 256 + threadIdx.x;
  if (i < n) rdeg[i] = rsqrtf((float)(deg[i] + 1));
}

// ---- 3-kernel exclusive scan of deg[n] -> row_start[n], block=256x4elems ----
__global__ void k_scan1(const int* __restrict__ deg, int* __restrict__ row_start,
                        int* __restrict__ bsum, int n) {
  __shared__ int s[256];
  int b = blockIdx.x, tid = threadIdx.x;
  int i0 = b * 1024 + tid * 4;
  int d0 = (i0 + 0 < n) ? deg[i0 + 0] : 0;
  int d1 = (i0 + 1 < n) ? deg[i0 + 1] : 0;
  int d2 = (i0 + 2 < n) ? deg[i0 + 2] : 0;
  int d3 = (i0 + 3 < n) ? deg[i0 + 3] : 0;
  int tsum = d0 + d1 + d2 + d3;
  s[tid] = tsum;
  __syncthreads();
  for (int off = 1; off < 256; off <<= 1) {
    int v = (tid >= off) ? s[tid - off] : 0;
    __syncthreads();
    s[tid] += v;
    __syncthreads();
  }
  int toff = s[tid] - tsum;  // exclusive prefix of this thread's 4
  if (i0 + 0 < n) row_start[i0 + 0] = toff;
  if (i0 + 1 < n) row_start[i0 + 1] = toff + d0;
  if (i0 + 2 < n) row_start[i0 + 2] = toff + d0 + d1;
  if (i0 + 3 < n) row_start[i0 + 3] = toff + d0 + d1 + d2;
  if (tid == 255) bsum[b] = s[255];
}

__global__ void k_scan2(int* __restrict__ bsum, int nb) {
  if (blockIdx.x == 0 && threadIdx.x == 0) {
    int run = 0;
    for (int i = 0; i < nb; ++i) { int v = bsum[i]; bsum[i] = run; run += v; }
  }
}

__global__ void k_scan3(int* __restrict__ row_start, int* __restrict__ cursor,
                        const int* __restrict__ bsum, int n) {
  int i = blockIdx.x * 256 + threadIdx.x;
  if (i < n) {
    int rs = row_start[i] + bsum[i >> 10];
    row_start[i] = rs;
    cursor[i] = rs;
  }
}

// Fill CSR: for each undirected edge (a,b) insert a into b's list and b into a's.
__global__ void k_fill_csr(const int2* __restrict__ edges, int* __restrict__ cursor,
                           int* __restrict__ csr, int E) {
  int e = blockIdx.x * 256 + threadIdx.x;
  if (e < E) {
    int2 ed = edges[e];
    int p0 = atomicAdd(&cursor[ed.y], 1);
    csr[p0] = ed.x;
    int p1 = atomicAdd(&cursor[ed.x], 1);
    csr[p1] = ed.y;
  }
}

// agg[d,:] = sum_{s in N(d)} x[s,:] * rdeg[s]   (self loop handled in k_gemm)
// One 128-thread block per destination row; thread t owns dim t.
__global__ void k_gather(const int* __restrict__ row_start, const int* __restrict__ deg,
                         const int* __restrict__ csr, const float* __restrict__ x,
                         const float* __restrict__ rdeg, float* __restrict__ agg) {
  int row = blockIdx.x;
  int tid = threadIdx.x;
  int rs = row_start[row];
  int de = deg[row];
  float acc = 0.f;
  int j = 0;
  for (; j + 1 < de; j += 2) {
    int s0 = csr[rs + j];
    int s1 = csr[rs + j + 1];
    float r0 = rdeg[s0], r1 = rdeg[s1];
    float v0 = x[(size_t)s0 * DIM_C + tid];
    float v1 = x[(size_t)s1 * DIM_C + tid];
    acc += v0 * r0 + v1 * r1;
  }
  if (j < de) {
    int s0 = csr[rs + j];
    acc += x[(size_t)s0 * DIM_C + tid] * rdeg[s0];
  }
  agg[(size_t)row * DIM_C + tid] = acc;
}

// dtype-flexible convert: src is fp32 (flag=1) or bf16 (flag=0) -> fp32 dst
__global__ void k_cvt_auto(const void* __restrict__ src, float* __restrict__ dst,
                           const int* __restrict__ flag, int n) {
  int i = blockIdx.x * 256 + threadIdx.x;
  if (i >= n) return;
  if (*flag) dst[i] = ((const float*)src)[i];
  else       dst[i] = __bfloat162float(((const bf16*)src)[i]);
}

// x = relu( A @ W + x ),  A[i,k] = rdeg[i]*agg[i,k] + rdeg[i]^2*x[i,k]
__global__ __launch_bounds__(256, 2) void k_gemm(
    float* __restrict__ x, const float* __restrict__ agg,
    const float* __restrict__ rdeg, const void* __restrict__ W,
    const int* __restrict__ flag, int n) {
  __shared__ float sW[64 * DIM_C];
  __shared__ float sA[32 * DIM_C];
  int isf32 = *flag;
  int row0 = blockIdx.x * 32;
  for (int i = threadIdx.x; i < 32 * DIM_C; i += 256) {
    int r = row0 + (i >> 7);
    int k = i & 127;
    float rd = rdeg[r];
    sA[i] = rd * agg[(size_t)r * DIM_C + k] + rd * rd * x[(size_t)r * DIM_C + k];
  }
  int tc = (threadIdx.x & 31) * 4;   // 4 output cols
  int tr = (threadIdx.x >> 5) * 4;   // 4 output rows
  float acc[4][4] = {};
  for (int kh = 0; kh < 2; ++kh) {
    __syncthreads();                  // sW reuse barrier (also covers sA on kh=0)
    for (int i = threadIdx.x; i < 64 * DIM_C; i += 256) {
      int off = kh * 64 * DIM_C + i;
      sW[i] = isf32 ? ((const float*)W)[off]
                    : __bfloat162float(((const bf16*)W)[off]);
    }
    __syncthreads();
#pragma unroll 8
    for (int k = 0; k < 64; ++k) {
      float4 w = *(const float4*)&sW[k * DIM_C + tc];
      int kk = kh * 64 + k;
      float a0 = sA[(tr + 0) * DIM_C + kk];
      float a1 = sA[(tr + 1) * DIM_C + kk];
      float a2 = sA[(tr + 2) * DIM_C + kk];
      float a3 = sA[(tr + 3) * DIM_C + kk];
      acc[0][0] = fmaf(a0, w.x, acc[0][0]); acc[0][1] = fmaf(a0, w.y, acc[0][1]);
      acc[0][2] = fmaf(a0, w.z, acc[0][2]); acc[0][3] = fmaf(a0, w.w, acc[0][3]);
      acc[1][0] = fmaf(a1, w.x, acc[1][0]); acc[1][1] = fmaf(a1, w.y, acc[1][1]);
      acc[1][2] = fmaf(a1, w.z, acc[1][2]); acc[1][3] = fmaf(a1, w.w, acc[1][3]);
      acc[2][0] = fmaf(a2, w.x, acc[2][0]); acc[2][1] = fmaf(a2, w.y, acc[2][1]);
      acc[2][2] = fmaf(a2, w.z, acc[2][2]); acc[2][3] = fmaf(a2, w.w, acc[2][3]);
      acc[3][0] = fmaf(a3, w.x, acc[3][0]); acc[3][1] = fmaf(a3, w.y, acc[3][1]);
      acc[3][2] = fmaf(a3, w.z, acc[3][2]); acc[3][3] = fmaf(a3, w.w, acc[3][3]);
    }
  }
  for (int r = 0; r < 4; ++r) {
    int row = row0 + tr + r;
    if (row >= n) break;
    float4 res = *(const float4*)&x[(size_t)row * DIM_C + tc];
    float4 o;
    o.x = fmaxf(acc[r][0] + res.x, 0.f);
    o.y = fmaxf(acc[r][1] + res.y, 0.f);
    o.z = fmaxf(acc[r][2] + res.z, 0.f);
    o.w = fmaxf(acc[r][3] + res.w, 0.f);
    *(float4*)&x[(size_t)row * DIM_C + tc] = o;
  }
}

__global__ void k_out_ent(const float4* __restrict__ x, float4* __restrict__ out, int n4) {
  int i = blockIdx.x * 256 + threadIdx.x;
  if (i < n4) out[i] = x[i];
}

__global__ void k_out_seed(const float* __restrict__ x, const int* __restrict__ seeds,
                           float* __restrict__ out, int total) {
  int t = blockIdx.x * 256 + threadIdx.x;
  if (t < total) {
    int s = t >> 7;
    int dim = t & 127;
    out[t] = x[(size_t)seeds[s] * DIM_C + dim];
  }
}

extern "C" void kernel_launch(void* const* d_in, const int* in_sizes, int n_in,
                              void* d_out, int out_size, void* d_ws, size_t ws_size,
                              hipStream_t stream) {
  const int*  sr_seeds = (const int*)d_in[0];
  const int*  tg_seeds = (const int*)d_in[1];
  // d_in[2], d_in[3]: triples_* — unused by the reference.
  const void* emb_sr   = d_in[4];
  const void* emb_tg   = d_in[5];
  const int*  edges_sr = (const int*)d_in[6];
  const int*  edges_tg = (const int*)d_in[7];
  const void* W1       = d_in[8];
  const void* W2       = d_in[9];
  float* out = (float*)d_out;

  const int nd = N_ENT_C * DIM_C;  // 12,800,000
  float* ws_x    = (float*)d_ws;
  float* ws_agg  = ws_x + (size_t)nd;
  float* ws_rdeg = ws_agg + (size_t)nd;
  int*   ws_flag = (int*)(ws_rdeg + N_ENT_C);   // ~102.8 MB of d_ws (same as R3)

  float* out_seed_sr = out;
  float* out_seed_tg = out + (size_t)N_SEED_C * DIM_C;
  float* out_ent_sr  = out + (size_t)2 * N_SEED_C * DIM_C;
  float* out_ent_tg  = out_ent_sr + (size_t)nd;

  const void* Ws[2] = {W1, W2};

  struct G { const void* emb; const int* edges; const int* seeds; float* oent; float* oseed; };
  G gs[2] = {
    {emb_sr, edges_sr, sr_seeds, out_ent_sr, out_seed_sr},
    {emb_tg, edges_tg, tg_seeds, out_ent_tg, out_seed_tg},
  };

  k_detect<<<1, 64, 0, stream>>>((const unsigned int*)emb_sr, ws_flag);

  const int NB_SCAN = (N_ENT_C + 1023) / 1024;  // 98

  for (int g = 0; g < 2; ++g) {
    // CSR scratch lives in THIS graph's out_ent region (dead until k_out_ent).
    int* sc        = (int*)gs[g].oent;          // 12.8M ints available
    int* csr       = sc;                        // [0, 1.0M)
    int* deg       = sc + 2 * N_EDGE_C;         // [1.0M, 1.1M)
    int* row_start = deg + N_ENT_C;             // [1.1M, 1.2M)
    int* cursor    = row_start + N_ENT_C;       // [1.2M, 1.3M)
    int* bsum      = cursor + N_ENT_C;          // [1.3M, +98)

    // ---- CSR build ----
    k_zero_int<<<(N_ENT_C + 255) / 256, 256, 0, stream>>>(deg, N_ENT_C);
    k_count   <<<(N_EDGE_C + 255) / 256, 256, 0, stream>>>((const int2*)gs[g].edges, deg, N_EDGE_C);
    k_rdeg    <<<(N_ENT_C + 255) / 256, 256, 0, stream>>>(deg, ws_rdeg, N_ENT_C);
    k_scan1   <<<NB_SCAN, 256, 0, stream>>>(deg, row_start, bsum, N_ENT_C);
    k_scan2   <<<1, 64, 0, stream>>>(bsum, NB_SCAN);
    k_scan3   <<<(N_ENT_C + 255) / 256, 256, 0, stream>>>(row_start, cursor, bsum, N_ENT_C);
    k_fill_csr<<<(N_EDGE_C + 255) / 256, 256, 0, stream>>>((const int2*)gs[g].edges, cursor, csr, N_EDGE_C);

    // ---- embeddings -> fp32 x ----
    k_cvt_auto<<<(nd + 255) / 256, 256, 0, stream>>>(gs[g].emb, ws_x, ws_flag, nd);

    // ---- 2 GCN layers ----
    for (int l = 0; l < 2; ++l) {
      k_gather<<<N_ENT_C, 128, 0, stream>>>(row_start, deg, csr, ws_x, ws_rdeg, ws_agg);
      k_gemm  <<<N_ENT_C / 32, 256, 0, stream>>>(ws_x, ws_agg, ws_rdeg, Ws[l], ws_flag, N_ENT_C);
    }

    // ---- outputs (k_out_ent overwrites the CSR scratch region - it's dead now) ----
    k_out_ent <<<(nd / 4 + 255) / 256, 256, 0, stream>>>((const float4*)ws_x, (float4*)gs[g].oent, nd / 4);
    k_out_seed<<<(N_SEED_C * DIM_C + 255) / 256, 256, 0, stream>>>(ws_x, gs[g].seeds, gs[g].oseed, N_SEED_C * DIM_C);
  }
}

// Round 5
// 1275.112 us; speedup vs baseline: 2.0416x; 1.0581x over previous
//
#include <hip/hip_runtime.h>
#include <hip/hip_bf16.h>

#define N_ENT_C   100000
#define N_EDGE_C  500000
#define N_SEED_C  10000
#define DIM_C     128

typedef unsigned int   u32;
typedef unsigned short u16;
typedef __attribute__((ext_vector_type(8))) short bf16x8;
typedef __attribute__((ext_vector_type(4))) float f32x4;

__device__ __forceinline__ float bflo(u32 v) { return __uint_as_float(v << 16); }
__device__ __forceinline__ float bfhi(u32 v) { return __uint_as_float(v & 0xFFFF0000u); }
__device__ __forceinline__ u16 f2bf(float f) {       // RNE
  u32 u = __float_as_uint(f);
  u += 0x7FFFu + ((u >> 16) & 1u);
  return (u16)(u >> 16);
}

// Detect whether a "float" input buffer is fp32 (flag=1) or packed bf16 (flag=0).
__global__ void k_detect(const u32* __restrict__ words, int* __restrict__ flag) {
  if (blockIdx.x == 0 && threadIdx.x == 0) {
    int cnt = 0;
    for (int i = 0; i < 64; ++i) {
      u32 e = (words[i] >> 7) & 0xFF;
      cnt += (e < 96) ? 1 : 0;
    }
    *flag = (cnt >= 8) ? 1 : 0;  // 1 = fp32, 0 = bf16
  }
}

__global__ void k_zero_int(int* __restrict__ p, int n) {
  int i = blockIdx.x * 256 + threadIdx.x;
  if (i < n) p[i] = 0;
}

__global__ void k_count(const int2* __restrict__ edges, int* __restrict__ deg, int E) {
  int e = blockIdx.x * 256 + threadIdx.x;
  if (e < E) {
    int2 ed = edges[e];
    atomicAdd(&deg[ed.x], 1);
    atomicAdd(&deg[ed.y], 1);
  }
}

__global__ void k_rdeg(const int* __restrict__ deg, float* __restrict__ rdeg, int n) {
  int i = blockIdx.x * 256 + threadIdx.x;
  if (i < n) rdeg[i] = rsqrtf((float)(deg[i] + 1));
}

// ---- 3-kernel exclusive scan of deg[n] -> row_start[n] ----
__global__ void k_scan1(const int* __restrict__ deg, int* __restrict__ row_start,
                        int* __restrict__ bsum, int n) {
  __shared__ int s[256];
  int b = blockIdx.x, tid = threadIdx.x;
  int i0 = b * 1024 + tid * 4;
  int d0 = (i0 + 0 < n) ? deg[i0 + 0] : 0;
  int d1 = (i0 + 1 < n) ? deg[i0 + 1] : 0;
  int d2 = (i0 + 2 < n) ? deg[i0 + 2] : 0;
  int d3 = (i0 + 3 < n) ? deg[i0 + 3] : 0;
  int tsum = d0 + d1 + d2 + d3;
  s[tid] = tsum;
  __syncthreads();
  for (int off = 1; off < 256; off <<= 1) {
    int v = (tid >= off) ? s[tid - off] : 0;
    __syncthreads();
    s[tid] += v;
    __syncthreads();
  }
  int toff = s[tid] - tsum;
  if (i0 + 0 < n) row_start[i0 + 0] = toff;
  if (i0 + 1 < n) row_start[i0 + 1] = toff + d0;
  if (i0 + 2 < n) row_start[i0 + 2] = toff + d0 + d1;
  if (i0 + 3 < n) row_start[i0 + 3] = toff + d0 + d1 + d2;
  if (tid == 255) bsum[b] = s[255];
}

__global__ void k_scan2(int* __restrict__ bsum, int nb) {
  if (blockIdx.x == 0 && threadIdx.x == 0) {
    int run = 0;
    for (int i = 0; i < nb; ++i) { int v = bsum[i]; bsum[i] = run; run += v; }
  }
}

__global__ void k_scan3(int* __restrict__ row_start, int* __restrict__ cursor,
                        const int* __restrict__ bsum, int n) {
  int i = blockIdx.x * 256 + threadIdx.x;
  if (i < n) {
    int rs = row_start[i] + bsum[i >> 10];
    row_start[i] = rs;
    cursor[i] = rs;
  }
}

__global__ void k_fill_csr(const int2* __restrict__ edges, int* __restrict__ cursor,
                           int* __restrict__ csr, int E) {
  int e = blockIdx.x * 256 + threadIdx.x;
  if (e < E) {
    int2 ed = edges[e];
    int p0 = atomicAdd(&cursor[ed.y], 1);
    csr[p0] = ed.x;
    int p1 = atomicAdd(&cursor[ed.x], 1);
    csr[p1] = ed.y;
  }
}

// emb (fp32 or bf16 per flag) -> packed bf16 x. i indexes uint pairs.
__global__ void k_cvt_bf16(const void* __restrict__ src, u32* __restrict__ dst,
                           const int* __restrict__ flag, int n2) {
  int i = blockIdx.x * 256 + threadIdx.x;
  if (i >= n2) return;
  if (*flag) {
    float2 v = ((const float2*)src)[i];
    dst[i] = (u32)f2bf(v.x) | ((u32)f2bf(v.y) << 16);
  } else {
    dst[i] = ((const u32*)src)[i];
  }
}

// Fused: per block of 32 rows -> gather+normalize into bf16 A-tile, MFMA with
// W^T (bf16 in LDS), residual + relu, write bf16 x_out.
// x_out = relu( A @ W + x_in ),  A[i,k] = rdeg[i]*sum_nbr + rdeg[i]^2*x_in[i,k]
__global__ __launch_bounds__(256, 3) void k_fused(
    const int* __restrict__ row_start, const int* __restrict__ deg,
    const int* __restrict__ csr, const u32* __restrict__ xin,
    const float* __restrict__ rdeg, const void* __restrict__ W,
    const int* __restrict__ flag, u32* __restrict__ xout) {
  // sWt: W^T [n][k] bf16, stride 136 (pad +8 keeps b128 reads at the 8-access
  // minimum and rows 16B-aligned). Reused as fp32 C [32][132] after MFMA.
  __shared__ __align__(16) u16 sWt[128 * 136];   // 34816 B
  __shared__ __align__(16) u16 sA[32 * 136];     //  8704 B  -> 42.5 KB, 3 blk/CU

  const int tid = threadIdx.x;
  const int row0 = blockIdx.x * 32;
  const int isf32 = *flag;

  // ---- stage W^T (bf16) ----
  {
    u32* sW32 = (u32*)sWt;
    const float* Wf = (const float*)W;
    const u16*   Wu = (const u16*)W;
    for (int i = tid; i < 64 * 128; i += 256) {
      int k2 = i >> 7;        // pair of k: 2*k2, 2*k2+1
      int n  = i & 127;
      u16 lo, hi;
      if (isf32) { lo = f2bf(Wf[(2 * k2) * 128 + n]); hi = f2bf(Wf[(2 * k2 + 1) * 128 + n]); }
      else       { lo = Wu[(2 * k2) * 128 + n];       hi = Wu[(2 * k2 + 1) * 128 + n]; }
      sW32[n * 68 + k2] = (u32)lo | ((u32)hi << 16);
    }
  }

  // ---- gather: wave w owns rows row0 + w + 4j ----
  const int wave = tid >> 6, lane = tid & 63;
  for (int j = 0; j < 8; ++j) {
    int row = row0 + wave + 4 * j;
    int rs = row_start[row];
    int de = deg[row];
    float a0 = 0.f, a1 = 0.f;
    int t = 0;
    for (; t + 1 < de; t += 2) {
      int s0 = csr[rs + t], s1 = csr[rs + t + 1];
      float r0 = rdeg[s0], r1 = rdeg[s1];
      u32 v0 = xin[(size_t)s0 * 64 + lane];
      u32 v1 = xin[(size_t)s1 * 64 + lane];
      a0 += r0 * bflo(v0) + r1 * bflo(v1);
      a1 += r0 * bfhi(v0) + r1 * bfhi(v1);
    }
    if (t < de) {
      int s0 = csr[rs + t];
      float r0 = rdeg[s0];
      u32 v0 = xin[(size_t)s0 * 64 + lane];
      a0 += r0 * bflo(v0);
      a1 += r0 * bfhi(v0);
    }
    float rd = rdeg[row];
    u32 vs = xin[(size_t)row * 64 + lane];
    a0 = rd * a0 + rd * rd * bflo(vs);
    a1 = rd * a1 + rd * rd * bfhi(vs);
    int rl = wave + 4 * j;
    ((u32*)sA)[rl * 68 + lane] = (u32)f2bf(a0) | ((u32)f2bf(a1) << 16);
  }
  __syncthreads();

  // ---- MFMA: wave -> 16 rows x 64 cols ----
  const int rows_h = (wave >> 1) * 16;   // 0 | 16
  const int col_q  = (wave & 1) * 64;    // 0 | 64
  const int m = lane & 15, q = lane >> 4;
  f32x4 acc[4];
  for (int ct = 0; ct < 4; ++ct) acc[ct] = (f32x4){0.f, 0.f, 0.f, 0.f};
#pragma unroll
  for (int kt = 0; kt < 4; ++kt) {
    int k0 = kt * 32 + q * 8;
    bf16x8 a = *(const bf16x8*)&sA[(rows_h + m) * 136 + k0];
#pragma unroll
    for (int ct = 0; ct < 4; ++ct) {
      bf16x8 b = *(const bf16x8*)&sWt[(col_q + ct * 16 + m) * 136 + k0];
      acc[ct] = __builtin_amdgcn_mfma_f32_16x16x32_bf16(a, b, acc[ct], 0, 0, 0);
    }
  }
  __syncthreads();   // all waves done reading sWt/sA before C overwrites sWt

  // ---- C (fp32) into LDS for coalesced epilogue ----
  float* sC = (float*)sWt;               // 32 x 132 fp32 = 16896 B
#pragma unroll
  for (int ct = 0; ct < 4; ++ct)
#pragma unroll
    for (int r = 0; r < 4; ++r)
      sC[(rows_h + q * 4 + r) * 132 + (col_q + ct * 16 + m)] = acc[ct][r];
  __syncthreads();

  // ---- epilogue: +residual, relu, pack bf16, coalesced store ----
  {
    int rowl = tid >> 3;
    int c0 = (tid & 7) * 16;
    size_t goff = (size_t)(row0 + rowl) * 64 + (c0 >> 1);  // in u32 units
    const u32* resp = xin + goff;
    u32 ov[8];
#pragma unroll
    for (int u = 0; u < 8; ++u) {
      u32 rv = resp[u];
      float lo = fmaxf(sC[rowl * 132 + c0 + 2 * u]     + bflo(rv), 0.f);
      float hi = fmaxf(sC[rowl * 132 + c0 + 2 * u + 1] + bfhi(rv), 0.f);
      ov[u] = (u32)f2bf(lo) | ((u32)f2bf(hi) << 16);
    }
    uint4* op = (uint4*)(xout + goff);
    op[0] = make_uint4(ov[0], ov[1], ov[2], ov[3]);
    op[1] = make_uint4(ov[4], ov[5], ov[6], ov[7]);
  }
}

__global__ void k_out_ent(const u32* __restrict__ x, float2* __restrict__ out, int n2) {
  int i = blockIdx.x * 256 + threadIdx.x;
  if (i < n2) {
    u32 v = x[i];
    out[i] = make_float2(bflo(v), bfhi(v));
  }
}

__global__ void k_out_seed(const u32* __restrict__ x, const int* __restrict__ seeds,
                           float2* __restrict__ out, int total2) {
  int t = blockIdx.x * 256 + threadIdx.x;
  if (t < total2) {
    int s = t >> 6, w = t & 63;
    u32 v = x[(size_t)seeds[s] * 64 + w];
    out[t] = make_float2(bflo(v), bfhi(v));
  }
}

extern "C" void kernel_launch(void* const* d_in, const int* in_sizes, int n_in,
                              void* d_out, int out_size, void* d_ws, size_t ws_size,
                              hipStream_t stream) {
  const int*  sr_seeds = (const int*)d_in[0];
  const int*  tg_seeds = (const int*)d_in[1];
  // d_in[2], d_in[3]: triples_* — unused by the reference.
  const void* emb_sr   = d_in[4];
  const void* emb_tg   = d_in[5];
  const int*  edges_sr = (const int*)d_in[6];
  const int*  edges_tg = (const int*)d_in[7];
  const void* W1       = d_in[8];
  const void* W2       = d_in[9];
  float* out = (float*)d_out;

  const int nd = N_ENT_C * DIM_C;  // 12,800,000
  // ws layout (~57 MB of >=102.8 MB proven):
  u16* x_a       = (u16*)d_ws;                    // 25.6 MB
  u16* x_b       = x_a + (size_t)nd;              // 25.6 MB
  float* ws_rdeg = (float*)(x_b + (size_t)nd);    // 400 KB
  int* ws_flag   = (int*)(ws_rdeg + N_ENT_C);
  int* deg       = ws_flag + 64;
  int* row_start = deg + N_ENT_C;
  int* cursor    = row_start + N_ENT_C;
  int* bsum      = cursor + N_ENT_C;
  int* csr       = bsum + 1024;                   // 4 MB

  float* out_seed_sr = out;
  float* out_seed_tg = out + (size_t)N_SEED_C * DIM_C;
  float* out_ent_sr  = out + (size_t)2 * N_SEED_C * DIM_C;
  float* out_ent_tg  = out_ent_sr + (size_t)nd;

  const void* Ws[2] = {W1, W2};

  struct G { const void* emb; const int* edges; const int* seeds; float* oent; float* oseed; };
  G gs[2] = {
    {emb_sr, edges_sr, sr_seeds, out_ent_sr, out_seed_sr},
    {emb_tg, edges_tg, tg_seeds, out_ent_tg, out_seed_tg},
  };

  k_detect<<<1, 64, 0, stream>>>((const u32*)emb_sr, ws_flag);

  const int NB_SCAN = (N_ENT_C + 1023) / 1024;  // 98

  for (int g = 0; g < 2; ++g) {
    // ---- CSR build ----
    k_zero_int<<<(N_ENT_C + 255) / 256, 256, 0, stream>>>(deg, N_ENT_C);
    k_count   <<<(N_EDGE_C + 255) / 256, 256, 0, stream>>>((const int2*)gs[g].edges, deg, N_EDGE_C);
    k_rdeg    <<<(N_ENT_C + 255) / 256, 256, 0, stream>>>(deg, ws_rdeg, N_ENT_C);
    k_scan1   <<<NB_SCAN, 256, 0, stream>>>(deg, row_start, bsum, N_ENT_C);
    k_scan2   <<<1, 64, 0, stream>>>(bsum, NB_SCAN);
    k_scan3   <<<(N_ENT_C + 255) / 256, 256, 0, stream>>>(row_start, cursor, bsum, N_ENT_C);
    k_fill_csr<<<(N_EDGE_C + 255) / 256, 256, 0, stream>>>((const int2*)gs[g].edges, cursor, csr, N_EDGE_C);

    // ---- embeddings -> bf16 x_a ----
    k_cvt_bf16<<<(nd / 2 + 255) / 256, 256, 0, stream>>>(gs[g].emb, (u32*)x_a, ws_flag, nd / 2);

    // ---- 2 fused GCN layers (x_a -> x_b -> x_a) ----
    k_fused<<<N_ENT_C / 32, 256, 0, stream>>>(row_start, deg, csr, (const u32*)x_a,
                                              ws_rdeg, Ws[0], ws_flag, (u32*)x_b);
    k_fused<<<N_ENT_C / 32, 256, 0, stream>>>(row_start, deg, csr, (const u32*)x_b,
                                              ws_rdeg, Ws[1], ws_flag, (u32*)x_a);

    // ---- outputs ----
    k_out_ent <<<(nd / 2 + 255) / 256, 256, 0, stream>>>((const u32*)x_a, (float2*)gs[g].oent, nd / 2);
    k_out_seed<<<(N_SEED_C * 64 + 255) / 256, 256, 0, stream>>>((const u32*)x_a, gs[g].seeds,
                                                                (float2*)gs[g].oseed, N_SEED_C * 64);
  }
}